// Round 1
// baseline (218.206 us; speedup 1.0000x reference)
//
#include <hip/hip_runtime.h>

// ContrastiveLoss on MI355X (gfx950)
// loss = (1/n) sum_i [ P_i * logz_i - (dot(e_i, C_{l_i})/T - 10) ]
//   logz_i = 10 + log( sum_{j != i} exp(sim_ij - 10) ),  sim_ij = (e_i . e_j)*10
//   C_k = sum of normalized embeddings with label k, P_i = count(label_i)-1
// Heavy part: z_i via fused bf16-MFMA GEMM + exp + row reduction (no sim matrix).

#define N 8192
#define D 128
#define INV_T 10.0f
#define JSPLIT 16

typedef __bf16 bf16x8 __attribute__((ext_vector_type(8)));
typedef float f32x4 __attribute__((ext_vector_type(4)));

// ws layout (bytes)
#define EBF_OFF   0          // bf16 normalized E: 8192*128*2 = 2097152
#define C_OFF     2097152    // class sums: 100*128*4 = 51200
#define CNT_OFF   2148352    // class counts: 100*4 (padded to 512)
#define Z_OFF     2148864    // z per row: 8192*4 = 32768
#define ZERO_OFF  C_OFF
#define ZERO_SZ   (CNT_OFF - C_OFF + 512 + 32768)   // C + cnt + z

__device__ __forceinline__ unsigned short f32_to_bf16_rne(float f) {
    unsigned int u = __float_as_uint(f);
    u += 0x7fffu + ((u >> 16) & 1u);
    return (unsigned short)(u >> 16);
}

// Kernel 1: normalize rows -> bf16 E; accumulate class sums + counts.
// One wave per row; lane handles 2 consecutive elements.
__global__ __launch_bounds__(256) void prep_kernel(
        const float* __restrict__ emb, const int* __restrict__ labels,
        unsigned short* __restrict__ ebf, float* __restrict__ C,
        int* __restrict__ cnt) {
    const int wave = threadIdx.x >> 6;
    const int lane = threadIdx.x & 63;
    const int row  = blockIdx.x * 4 + wave;

    const float2 v = *(const float2*)(emb + (size_t)row * D + lane * 2);
    float ss = v.x * v.x + v.y * v.y;
    #pragma unroll
    for (int off = 32; off; off >>= 1) ss += __shfl_xor(ss, off);
    const float inv = 1.0f / fmaxf(sqrtf(ss), 1e-12f);
    const float x0 = v.x * inv, x1 = v.y * inv;

    unsigned int packed = (unsigned int)f32_to_bf16_rne(x0) |
                          ((unsigned int)f32_to_bf16_rne(x1) << 16);
    ((unsigned int*)ebf)[row * (D / 2) + lane] = packed;

    const int lab = labels[row];
    atomicAdd(&C[lab * D + lane * 2],     x0);
    atomicAdd(&C[lab * D + lane * 2 + 1], x1);
    if (lane == 0) atomicAdd(&cnt[lab], 1);
}

// Kernel 2: z_i = sum_{j != i} exp(sim_ij - 10) via 16x16x32 bf16 MFMA.
// Block = 4 waves; wave owns a 16-row i-strip (64 rows/block).
// grid.y splits the j sweep; partial z via atomicAdd.
// Fragment layouts (measured, learn_hip m89/m91/m120):
//   A/B operand: idx = lane&15, k = (lane>>4)*8 + j
//   C/D:         col = lane&15, row = (lane>>4)*4 + reg
__global__ __launch_bounds__(256) void zsum_kernel(
        const unsigned short* __restrict__ ebf, float* __restrict__ z) {
    const int wave = threadIdx.x >> 6;
    const int lane = threadIdx.x & 63;
    const int q    = lane >> 4;
    const int col  = lane & 15;
    const int i0   = blockIdx.x * 64 + wave * 16;

    // A fragments for this wave's 16-row strip (K=128 -> 4 chunks of 32)
    bf16x8 a[4];
    const unsigned short* arow = ebf + (size_t)(i0 + col) * D + q * 8;
    #pragma unroll
    for (int c = 0; c < 4; ++c) a[c] = *(const bf16x8*)(arow + c * 32);

    float zacc[4] = {0.f, 0.f, 0.f, 0.f};
    const int jbase   = blockIdx.y * (N / JSPLIT);
    const int ntiles  = (N / JSPLIT) / 16;

    for (int jt = 0; jt < ntiles; ++jt) {
        const int j0 = jbase + jt * 16;
        const unsigned short* brow = ebf + (size_t)(j0 + col) * D + q * 8;
        bf16x8 b[4];
        #pragma unroll
        for (int c = 0; c < 4; ++c) b[c] = *(const bf16x8*)(brow + c * 32);

        f32x4 acc = {0.f, 0.f, 0.f, 0.f};
        #pragma unroll
        for (int c = 0; c < 4; ++c)
            acc = __builtin_amdgcn_mfma_f32_16x16x32_bf16(a[c], b[c], acc, 0, 0, 0);

        #pragma unroll
        for (int r = 0; r < 4; ++r) {
            const int gi = i0 + q * 4 + r;
            const int gj = j0 + col;
            const float e = __expf(acc[r] * INV_T - 10.0f);
            zacc[r] += (gi == gj) ? 0.0f : e;   // mask diagonal
        }
    }

    // Row sums: reduce across the 16 lanes of each quad (cols of the tile)
    #pragma unroll
    for (int r = 0; r < 4; ++r) {
        float v = zacc[r];
        v += __shfl_xor(v, 1);
        v += __shfl_xor(v, 2);
        v += __shfl_xor(v, 4);
        v += __shfl_xor(v, 8);
        if (col == 0) atomicAdd(&z[i0 + q * 4 + r], v);
    }
}

// Kernel 3: assemble loss. Wave handles 4 rows sequentially; block=4 waves=16 rows.
__global__ __launch_bounds__(256) void loss_kernel(
        const float* __restrict__ emb, const int* __restrict__ labels,
        const float* __restrict__ C, const int* __restrict__ cnt,
        const float* __restrict__ z, float* __restrict__ out) {
    __shared__ float part[4];
    const int wave = threadIdx.x >> 6;
    const int lane = threadIdx.x & 63;

    float wsum = 0.0f;
    #pragma unroll
    for (int r = 0; r < 4; ++r) {
        const int row = blockIdx.x * 16 + wave * 4 + r;
        const int lab = labels[row];
        const float2 v  = *(const float2*)(emb + (size_t)row * D + lane * 2);
        const float2 c2 = *(const float2*)(C   + (size_t)lab * D + lane * 2);
        float ss = v.x * v.x + v.y * v.y;
        float d  = v.x * c2.x + v.y * c2.y;
        #pragma unroll
        for (int off = 32; off; off >>= 1) {
            ss += __shfl_xor(ss, off);
            d  += __shfl_xor(d,  off);
        }
        if (lane == 0) {
            const int P = cnt[lab] - 1;
            if (P > 0) {
                const float inv  = 1.0f / fmaxf(sqrtf(ss), 1e-12f);
                const float logz = 10.0f + logf(z[row]);
                const float S    = (d * inv) * INV_T - 10.0f;  // positive-sum minus self
                wsum += (float)P * logz - S;
            }
        }
    }
    if (lane == 0) part[wave] = wsum;
    __syncthreads();
    if (threadIdx.x == 0) {
        const float t = part[0] + part[1] + part[2] + part[3];
        atomicAdd(out, t * (1.0f / (float)N));
    }
}

extern "C" void kernel_launch(void* const* d_in, const int* in_sizes, int n_in,
                              void* d_out, int out_size, void* d_ws, size_t ws_size,
                              hipStream_t stream) {
    const float* emb   = (const float*)d_in[0];
    const int* labels  = (const int*)d_in[1];
    float* out         = (float*)d_out;
    char* ws           = (char*)d_ws;

    unsigned short* ebf = (unsigned short*)(ws + EBF_OFF);
    float* C            = (float*)(ws + C_OFF);
    int*   cnt          = (int*)(ws + CNT_OFF);
    float* z            = (float*)(ws + Z_OFF);

    hipMemsetAsync(ws + ZERO_OFF, 0, ZERO_SZ, stream);
    hipMemsetAsync(d_out, 0, sizeof(float), stream);

    prep_kernel<<<N / 4, 256, 0, stream>>>(emb, labels, ebf, C, cnt);
    zsum_kernel<<<dim3(N / 64, JSPLIT), 256, 0, stream>>>(ebf, z);
    loss_kernel<<<N / 16, 256, 0, stream>>>(emb, labels, C, cnt, z, out);
}

// Round 2
// 180.516 us; speedup vs baseline: 1.2088x; 1.2088x over previous
//
#include <hip/hip_runtime.h>

// ContrastiveLoss on MI355X (gfx950) — round 2
// loss = (1/n) sum_i [ P_i * logz_i - (dot(e_i, C_{l_i})/T - 10) ]
//   logz_i = 10 + log( sum_{j != i} exp(sim_ij - 10) ),  sim_ij = (e_i . e_j)*10
// zsum: 128x128 block tile, B staged in LDS via global_load_lds(16B),
// E stored in MFMA-fragment-major layout so staging is a linear copy and
// ds_read_b128 fragment reads are phase-linear (conflict-free).

#define N 8192
#define D 128
#define JSPLIT 16
#define IBLK 128          // i-rows per block (4 waves x 32)
#define JTILE 128         // j-rows per LDS tile (32 KB)
#define K2E 14.4269504088896340736f   // 10*log2(e)

typedef __bf16 bf16x8 __attribute__((ext_vector_type(8)));
typedef float f32x4 __attribute__((ext_vector_type(4)));

// ws layout (bytes)
#define EBF_OFF   0          // bf16 E, fragment-major: 8192*128*2 = 2097152
#define C_OFF     2097152    // class sums: 100*128*4 = 51200
#define CNT_OFF   2148352    // class counts: 100*4 (padded to 512)
#define Z_OFF     2148864    // z per row: 8192*4 = 32768
#define ZERO_SZ   (51200 + 512 + 32768)

__device__ __forceinline__ unsigned short f32_to_bf16_rne(float f) {
    unsigned int u = __float_as_uint(f);
    u += 0x7fffu + ((u >> 16) & 1u);
    return (unsigned short)(u >> 16);
}

__device__ __forceinline__ float fast_exp2(float x) {
#if __has_builtin(__builtin_amdgcn_exp2f)
    return __builtin_amdgcn_exp2f(x);
#else
    return exp2f(x);
#endif
}

// Fragment-major layout of E:
//   row r -> group grp = r>>4, col = r&15
//   element k -> chunk c = k>>5, quad q = (k>>3)&3, jj = k&7
//   byte offset = grp*4096 + c*1024 + q*256 + col*16 + jj*2
// A/B fragment (chunk c) for a wave: lane (q*16+col) reads 16B at
//   grp*4096 + c*1024 + lane*16   -> contiguous 1KB per chunk.

// Kernel 1: normalize rows -> fragment-major bf16 E; class sums + counts.
// One wave per row; lane handles elements 2l, 2l+1.
__global__ __launch_bounds__(256) void prep_kernel(
        const float* __restrict__ emb, const int* __restrict__ labels,
        unsigned char* __restrict__ ebf, float* __restrict__ C,
        int* __restrict__ cnt) {
    const int wave = threadIdx.x >> 6;
    const int lane = threadIdx.x & 63;
    const int row  = blockIdx.x * 4 + wave;

    const float2 v = *(const float2*)(emb + (size_t)row * D + lane * 2);
    float ss = v.x * v.x + v.y * v.y;
    #pragma unroll
    for (int off = 32; off; off >>= 1) ss += __shfl_xor(ss, off);
    const float inv = 1.0f / fmaxf(sqrtf(ss), 1e-12f);

    // fragment-major write (elements 2l, 2l+1 share one 16B slot)
    const int grp = row >> 4, col = row & 15;
    const int c = lane >> 4, q = (lane >> 2) & 3, j2 = lane & 3;
    unsigned int packed = (unsigned int)f32_to_bf16_rne(v.x * inv) |
                          ((unsigned int)f32_to_bf16_rne(v.y * inv) << 16);
    *(unsigned int*)(ebf + grp * 4096 + c * 1024 + q * 256 + col * 16 + j2 * 4) = packed;

    // class sums with per-row element rotation to de-hotspot atomics
    const int lab = labels[row];
    const int e0  = (lane * 2 + row * 2) & (D - 1);   // even
    const float2 w2 = *(const float2*)(emb + (size_t)row * D + e0);
    atomicAdd(&C[lab * D + e0],     w2.x * inv);
    atomicAdd(&C[lab * D + e0 + 1], w2.y * inv);
    if (lane == 0) atomicAdd(&cnt[lab], 1);
}

// Kernel 2: z_i = sum_{j != i} exp(10*sim_ij - 10), fused MFMA GEMM.
// Block: 4 waves, 128 i-rows (32/wave). j-range = 512 rows (blockIdx.y),
// processed as 4 LDS tiles of 128 rows staged with global_load_lds.
__global__ __launch_bounds__(256, 4) void zsum_kernel(
        const unsigned char* __restrict__ ebf, float* __restrict__ z) {
    __shared__ __align__(16) unsigned char sm[JTILE * 256];   // 32 KB

    const int t    = threadIdx.x;
    const int w    = t >> 6;
    const int lane = t & 63;
    const int q    = lane >> 4;
    const int col  = lane & 15;
    const int i0   = blockIdx.x * IBLK;
    const int jb   = blockIdx.y * (N / JSPLIT);

    // A fragments: 2 groups of 16 i-rows, 4 K-chunks each (coalesced 1KB loads)
    bf16x8 a[2][4];
    #pragma unroll
    for (int g = 0; g < 2; ++g) {
        const unsigned char* ag = ebf + (i0 / 16 + w * 2 + g) * 4096 + lane * 16;
        #pragma unroll
        for (int c = 0; c < 4; ++c) a[g][c] = *(const bf16x8*)(ag + c * 1024);
    }

    float zacc[2][4] = {{0.f, 0.f, 0.f, 0.f}, {0.f, 0.f, 0.f, 0.f}};

    for (int jt = 0; jt < (N / JSPLIT) / JTILE; ++jt) {
        const int j0 = jb + jt * JTILE;
        if (jt) __syncthreads();                     // protect LDS reuse
        // stage 32 KB: linear copy, 16B per lane per issue
        const unsigned char* gsrc = ebf + j0 * 256 + t * 16;
        unsigned char* ldst = sm + (t & ~63) * 16;   // wave-uniform base + lane*16
        #pragma unroll
        for (int it = 0; it < 8; ++it)
            __builtin_amdgcn_global_load_lds(
                (const __attribute__((address_space(1))) void*)(gsrc + it * 4096),
                (__attribute__((address_space(3))) void*)(ldst + it * 4096),
                16, 0, 0);
        __syncthreads();

        #pragma unroll
        for (int s = 0; s < 8; ++s) {
            bf16x8 b[4];
            #pragma unroll
            for (int c = 0; c < 4; ++c)
                b[c] = *(const bf16x8*)(sm + s * 4096 + c * 1024 + lane * 16);
            const int js = j0 + s * 16;
            #pragma unroll
            for (int g = 0; g < 2; ++g) {
                f32x4 acc = {0.f, 0.f, 0.f, 0.f};
                #pragma unroll
                for (int c = 0; c < 4; ++c)
                    acc = __builtin_amdgcn_mfma_f32_16x16x32_bf16(a[g][c], b[c], acc, 0, 0, 0);
                const int ig = i0 + w * 32 + g * 16;
                if (js == ig) {                      // wave-uniform; rare path
                    #pragma unroll
                    for (int r = 0; r < 4; ++r) {
                        const float e = fast_exp2(fmaf(acc[r], K2E, -K2E));
                        zacc[g][r] += (col == q * 4 + r) ? 0.0f : e;
                    }
                } else {
                    #pragma unroll
                    for (int r = 0; r < 4; ++r)
                        zacc[g][r] += fast_exp2(fmaf(acc[r], K2E, -K2E));
                }
            }
        }
    }

    // row sums across the 16 cols of each quad, then atomic merge
    #pragma unroll
    for (int g = 0; g < 2; ++g)
        #pragma unroll
        for (int r = 0; r < 4; ++r) {
            float v = zacc[g][r];
            v += __shfl_xor(v, 1);
            v += __shfl_xor(v, 2);
            v += __shfl_xor(v, 4);
            v += __shfl_xor(v, 8);
            if (col == 0) atomicAdd(&z[i0 + w * 32 + g * 16 + q * 4 + r], v);
        }
}

// Kernel 3: assemble loss. Wave handles 4 rows; block = 16 rows.
__global__ __launch_bounds__(256) void loss_kernel(
        const float* __restrict__ emb, const int* __restrict__ labels,
        const float* __restrict__ C, const int* __restrict__ cnt,
        const float* __restrict__ z, float* __restrict__ out) {
    __shared__ float part[4];
    const int wave = threadIdx.x >> 6;
    const int lane = threadIdx.x & 63;

    float wsum = 0.0f;
    #pragma unroll
    for (int r = 0; r < 4; ++r) {
        const int row = blockIdx.x * 16 + wave * 4 + r;
        const int lab = labels[row];
        const float2 v  = *(const float2*)(emb + (size_t)row * D + lane * 2);
        const float2 c2 = *(const float2*)(C   + (size_t)lab * D + lane * 2);
        float ss = v.x * v.x + v.y * v.y;
        float d  = v.x * c2.x + v.y * c2.y;
        #pragma unroll
        for (int off = 32; off; off >>= 1) {
            ss += __shfl_xor(ss, off);
            d  += __shfl_xor(d,  off);
        }
        if (lane == 0) {
            const int P = cnt[lab] - 1;
            if (P > 0) {
                const float inv  = 1.0f / fmaxf(sqrtf(ss), 1e-12f);
                const float logz = 10.0f + logf(z[row]);
                const float S    = (d * inv) * 10.0f - 10.0f;  // pos-sum minus self
                wsum += (float)P * logz - S;
            }
        }
    }
    if (lane == 0) part[wave] = wsum;
    __syncthreads();
    if (threadIdx.x == 0) {
        const float tt = part[0] + part[1] + part[2] + part[3];
        atomicAdd(out, tt * (1.0f / (float)N));
    }
}

extern "C" void kernel_launch(void* const* d_in, const int* in_sizes, int n_in,
                              void* d_out, int out_size, void* d_ws, size_t ws_size,
                              hipStream_t stream) {
    const float* emb  = (const float*)d_in[0];
    const int* labels = (const int*)d_in[1];
    float* out        = (float*)d_out;
    char* ws          = (char*)d_ws;

    unsigned char* ebf = (unsigned char*)(ws + EBF_OFF);
    float* C           = (float*)(ws + C_OFF);
    int*   cnt         = (int*)(ws + CNT_OFF);
    float* z           = (float*)(ws + Z_OFF);

    hipMemsetAsync(ws + C_OFF, 0, ZERO_SZ, stream);
    hipMemsetAsync(d_out, 0, sizeof(float), stream);

    prep_kernel<<<N / 4, 256, 0, stream>>>(emb, labels, ebf, C, cnt);
    zsum_kernel<<<dim3(N / IBLK, JSPLIT), 256, 0, stream>>>(ebf, z);
    loss_kernel<<<N / 16, 256, 0, stream>>>(emb, labels, C, cnt, z, out);
}